// Round 1
// baseline (87.696 us; speedup 1.0000x reference)
//
#include <hip/hip_runtime.h>

// Quanvolution + linear(784->10) + log_softmax, B=65536.
// Memory-bound: read x once (205 MB), write out (2.6 MB). Target ~33-40 us.
//
// Decomposition: 512 blocks x 256 threads. Block owns 128 rows.
// Thread t: row r = t&127, half h = t>>7 (wave-uniform). Half 0 processes
// patch-rows 0..6, half 1 processes 7..13. 7 iterations; each stages two
// 56-float panels (one per half) into LDS via coalesced float4 loads.
// W is read with wave-uniform addresses -> scalar loads (K$ broadcast).

#define THREADS 256
#define RB 128            // rows per block
#define PAD 58            // LDS row stride in floats (56 data + 2 pad)

__global__ __launch_bounds__(THREADS, 2)
void quanv_fused_kernel(const float* __restrict__ x,
                        const float* __restrict__ W,
                        const float* __restrict__ bias,
                        float* __restrict__ out) {
    __shared__ float sm[2 * RB * PAD];   // 59392 B

    const int t  = threadIdx.x;
    const int R0 = blockIdx.x * RB;
    const int r  = t & (RB - 1);
    // half id: wave-uniform (waves 0,1 -> h=0 ; waves 2,3 -> h=1)
    const int h  = __builtin_amdgcn_readfirstlane(t >> 7);

    float acc[10];
#pragma unroll
    for (int k = 0; k < 10; ++k) acc[k] = 0.f;

    for (int i = 0; i < 7; ++i) {
        // ---- stage: panel p covers patch-row (p*7 + i) for all 128 rows ----
        // per panel: 128 rows x 56 floats = 1792 float4 -> 7 float4/thread
#pragma unroll
        for (int p = 0; p < 2; ++p) {
            const int pr = p * 7 + i;
            const float* src = x + (size_t)R0 * 784 + pr * 56;
            float* dst = &sm[p * RB * PAD];
#pragma unroll
            for (int j = 0; j < 7; ++j) {
                const int f   = t + j * THREADS;   // 0..1791
                const int row = f / 14;
                const int cg  = f - row * 14;      // 0..13
                const float4 v = *(const float4*)(src + (size_t)row * 784 + cg * 4);
                float* d = dst + row * PAD + cg * 4;
                *(float2*)(d)     = make_float2(v.x, v.y);
                *(float2*)(d + 2) = make_float2(v.z, v.w);
            }
        }
        __syncthreads();

        // ---- compute: my half's patch-row, 14 patches ----
        const float* myrow = &sm[h * RB * PAD + r * PAD];
        const int Pbase = (h * 7 + i) * 14;        // wave-uniform patch base
#pragma unroll
        for (int pj = 0; pj < 14; ++pj) {
            const float2 a = *(const float2*)(myrow + 2 * pj);        // p0,p1
            const float2 q = *(const float2*)(myrow + 28 + 2 * pj);   // p2,p3
            const float c0 = __cosf(a.x), c1 = __cosf(a.y);
            const float c2 = __cosf(q.x), c3 = __cosf(q.y);
            const float f0 = c0 + a.x;
            const float f1 = c0 * c1 + a.y;
            const float f2 = c2 + q.x;
            const float f3 = c2 * c3 + q.y;
            const int P = Pbase + pj;              // wave-uniform -> s_load W
#pragma unroll
            for (int k = 0; k < 10; ++k) {
                const float4 w = *(const float4*)(W + k * 784 + P * 4);
                acc[k] += f0 * w.x + f1 * w.y + f2 * w.z + f3 * w.w;
            }
        }
        __syncthreads();
    }

    // ---- combine halves + bias + log_softmax + store ----
    if (h == 1) {
#pragma unroll
        for (int k = 0; k < 10; ++k) sm[r * 10 + k] = acc[k];
    }
    __syncthreads();
    if (h == 0) {
        float m = -1e30f;
#pragma unroll
        for (int k = 0; k < 10; ++k) {
            acc[k] += sm[r * 10 + k] + bias[k];
            m = fmaxf(m, acc[k]);
        }
        float s = 0.f;
#pragma unroll
        for (int k = 0; k < 10; ++k) s += __expf(acc[k] - m);
        const float ls = __logf(s) + m;
        float* o = out + (size_t)(R0 + r) * 10;
#pragma unroll
        for (int k = 0; k < 10; ++k) o[k] = acc[k] - ls;
    }
}

extern "C" void kernel_launch(void* const* d_in, const int* in_sizes, int n_in,
                              void* d_out, int out_size, void* d_ws, size_t ws_size,
                              hipStream_t stream) {
    const float* x    = (const float*)d_in[0];   // [65536, 784]
    const float* W    = (const float*)d_in[1];   // [10, 784]
    const float* bias = (const float*)d_in[2];   // [10]
    float* out        = (float*)d_out;           // [65536, 10]

    quanv_fused_kernel<<<dim3(512), dim3(THREADS), 0, stream>>>(x, W, bias, out);
}